// Round 3
// baseline (931.008 us; speedup 1.0000x reference)
//
#include <hip/hip_runtime.h>
#include <hip/hip_bf16.h>

typedef __bf16 bf16x8 __attribute__((ext_vector_type(8)));
typedef float f32x4 __attribute__((ext_vector_type(4)));
using u16 = unsigned short;

__device__ __forceinline__ float bf2f(u16 v) {
    unsigned int u = (unsigned int)v << 16;
    float f; __builtin_memcpy(&f, &u, 4); return f;
}
__device__ __forceinline__ u16 f2bf(float f) {
    unsigned int u; __builtin_memcpy(&u, &f, 4);
    u += 0x7FFFu + ((u >> 16) & 1u);   // RNE (finite data only)
    return (u16)(u >> 16);
}

// ---------------------------------------------------------------------------
// Generic C = A @ B^T + bias GEMM.  AF/BF: operand stored as fp32 (converted
// to bf16 during LDS staging); else bf16 (u16).  CF: C stored fp32, else bf16.
// A: M x K (lda), B: N x K (ldb, torch nn.Linear weight), bias fp32.
// M multiple of 128; N guarded.  128x128 tile, BK=32, 4 waves, 4x4 grid of
// 16x16x32 bf16 MFMA per wave.  LDS row stride 40 (16B-aligned b128 reads).
// ---------------------------------------------------------------------------
template<bool AF, bool BF, bool CF>
__global__ __launch_bounds__(256) void gemm_bt(
    const void* __restrict__ Av, int lda,
    const void* __restrict__ Bv, int ldb,
    void* __restrict__ Cv, int ldc,
    int N, int K,
    const float* __restrict__ bias)
{
    __shared__ __align__(16) u16 As[128 * 40];
    __shared__ __align__(16) u16 Bs[128 * 40];

    const int t = threadIdx.x;
    const int lane = t & 63;
    const int w = t >> 6;
    const int wm = w >> 1, wn = w & 1;
    const int l16 = lane & 15, quad = lane >> 4;
    const int m0 = blockIdx.x * 128;
    const int n0 = blockIdx.y * 128;

    f32x4 acc[4][4];
#pragma unroll
    for (int i = 0; i < 4; ++i)
#pragma unroll
        for (int j = 0; j < 4; ++j) acc[i][j] = (f32x4){0.f, 0.f, 0.f, 0.f};

    for (int k0 = 0; k0 < K; k0 += 32) {
        __syncthreads();
#pragma unroll
        for (int p = 0; p < 2; ++p) {
            int ch = t + 256 * p;
            int row = ch >> 2;
            int cc = ch & 3;
            // ---- A chunk: 8 elements at (m0+row, k0+cc*8) ----
            if (AF) {
                const float* ap = (const float*)Av + (size_t)(m0 + row) * lda + k0 + cc * 8;
                float4 f0 = *(const float4*)ap;
                float4 f1 = *(const float4*)(ap + 4);
                u16 tmp[8] = { f2bf(f0.x), f2bf(f0.y), f2bf(f0.z), f2bf(f0.w),
                               f2bf(f1.x), f2bf(f1.y), f2bf(f1.z), f2bf(f1.w) };
                *(uint4*)&As[row * 40 + cc * 8] = *(const uint4*)tmp;
            } else {
                uint4 va = *(const uint4*)((const u16*)Av + (size_t)(m0 + row) * lda + k0 + cc * 8);
                *(uint4*)&As[row * 40 + cc * 8] = va;
            }
            // ---- B chunk: 8 elements at (n0+row, k0+cc*8), N-guarded ----
            int gn = n0 + row;
            if (BF) {
                u16 tmp[8] = {0,0,0,0,0,0,0,0};
                if (gn < N) {
                    const float* bp = (const float*)Bv + (size_t)gn * ldb + k0 + cc * 8;
                    float4 f0 = *(const float4*)bp;
                    float4 f1 = *(const float4*)(bp + 4);
                    tmp[0]=f2bf(f0.x); tmp[1]=f2bf(f0.y); tmp[2]=f2bf(f0.z); tmp[3]=f2bf(f0.w);
                    tmp[4]=f2bf(f1.x); tmp[5]=f2bf(f1.y); tmp[6]=f2bf(f1.z); tmp[7]=f2bf(f1.w);
                }
                *(uint4*)&Bs[row * 40 + cc * 8] = *(const uint4*)tmp;
            } else {
                uint4 vb = make_uint4(0u, 0u, 0u, 0u);
                if (gn < N) vb = *(const uint4*)((const u16*)Bv + (size_t)gn * ldb + k0 + cc * 8);
                *(uint4*)&Bs[row * 40 + cc * 8] = vb;
            }
        }
        __syncthreads();

        bf16x8 af[4], bfr[4];
#pragma unroll
        for (int i = 0; i < 4; ++i)
            af[i] = *(const bf16x8*)&As[(wm * 64 + i * 16 + l16) * 40 + quad * 8];
#pragma unroll
        for (int j = 0; j < 4; ++j)
            bfr[j] = *(const bf16x8*)&Bs[(wn * 64 + j * 16 + l16) * 40 + quad * 8];
#pragma unroll
        for (int i = 0; i < 4; ++i)
#pragma unroll
            for (int j = 0; j < 4; ++j)
                acc[i][j] = __builtin_amdgcn_mfma_f32_16x16x32_bf16(af[i], bfr[j], acc[i][j], 0, 0, 0);
    }

#pragma unroll
    for (int j = 0; j < 4; ++j) {
        int col = n0 + wn * 64 + j * 16 + l16;
        if (col >= N) continue;
        float bv = bias[col];
#pragma unroll
        for (int i = 0; i < 4; ++i) {
#pragma unroll
            for (int r = 0; r < 4; ++r) {
                int row = m0 + wm * 64 + i * 16 + quad * 4 + r;
                float v = acc[i][j][r] + bv;
                if (CF) ((float*)Cv)[(size_t)row * ldc + col] = v;
                else    ((u16*)Cv)[(size_t)row * ldc + col] = f2bf(v);
            }
        }
    }
}

// ---------------------------------------------------------------------------
// RoPE in place on bf16 ws buffers, faithful to the source quirk (cos_pos =
// sin(ang), sin_pos = cos(ang)):  out[2i] = x[2i]*sin - x[2i+1]*cos ;
// out[2i+1] = x[2i+1]*sin + x[2i]*cos ;  ang = (row % 512) * 10000^(-i/32).
// ---------------------------------------------------------------------------
__global__ void rope_inplace(u16* __restrict__ buf, int ld, int col0, int ppr, int total)
{
    int idx = blockIdx.x * 256 + threadIdx.x;
    if (idx >= total) return;
    int row = idx / ppr;
    int pi  = idx - row * ppr;
    int grp = pi >> 5;
    int i   = pi & 31;
    int pos = row & 511;
    float theta = __expf(-(float)i * 0.2878231366242558f);  // ln(10000)/32
    float ang = (float)pos * theta;
    float s = sinf(ang), c = cosf(ang);
    size_t base = (size_t)row * ld + col0 + grp * 64 + 2 * i;
    float x0 = bf2f(buf[base]);
    float x1 = bf2f(buf[base + 1]);
    buf[base]     = f2bf(x0 * s - x1 * c);
    buf[base + 1] = f2bf(x1 * s + x0 * c);
}

// ---------------------------------------------------------------------------
// Flash attention (all operands bf16 in ws).  One WG = (b, h, 64-row q tile),
// 4 waves; wave w owns a 16-row q strip.  64-key tiles, online softmax,
// P: C-layout -> LDS -> A-layout; V staged transposed for b128 b-frags.
// Output into o_dst cols 0..1023 (aliases out1's dead c_kv/c_q region; this
// kernel only READS out1 cols 1024..1087, byte-disjoint from the writes).
// ---------------------------------------------------------------------------
__global__ __launch_bounds__(256) void attn_kernel(
    const u16* __restrict__ q_src,   // 8192 x 2048 : [q_c | q_r(roped)]
    const u16* __restrict__ kv_src,  // 8192 x 2048 : [k_c | v_c]
    const u16* __restrict__ kr_src,  // 8192 x 1088 : k_r at col 1024 (roped)
    u16* __restrict__ o_dst, int ldo)
{
    __shared__ __align__(16) u16 Qs[64 * 136];
    __shared__ __align__(16) u16 Ks[64 * 136];
    __shared__ __align__(16) u16 Vt[64 * 72];   // [vd][key]
    __shared__ __align__(16) u16 Ps[64 * 72];   // [q][key]

    const int t = threadIdx.x;
    const int lane = t & 63;
    const int w = t >> 6;
    const int l16 = lane & 15, quad = lane >> 4;
    const int qt = blockIdx.x;   // 0..7
    const int h  = blockIdx.y;   // 0..15
    const int b  = blockIdx.z;   // 0..15
    const int qrow0 = b * 512 + qt * 64;

    // Q tile: 64 x 128 = [q_c | q_r]
#pragma unroll
    for (int p = 0; p < 4; ++p) {
        int ch = t + 256 * p;
        int r = ch >> 4;
        int col = (ch & 15) * 8;
        const u16* src = (col < 64)
            ? q_src + (size_t)(qrow0 + r) * 2048 + h * 64 + col
            : q_src + (size_t)(qrow0 + r) * 2048 + 1024 + h * 64 + (col - 64);
        *(uint4*)&Qs[r * 136 + col] = *(const uint4*)src;
    }

    float m_run[4], l_run[4];
    f32x4 o[4];
#pragma unroll
    for (int r = 0; r < 4; ++r) { m_run[r] = -1e30f; l_run[r] = 0.f; }
#pragma unroll
    for (int n = 0; n < 4; ++n) o[n] = (f32x4){0.f, 0.f, 0.f, 0.f};

    const float scale = 0.07216878364870323f;  // 1/sqrt(192)

    for (int kt = 0; kt < 8; ++kt) {
        __syncthreads();  // prev iter done with Ks/Vt/Ps; also orders Q staging
        const int krow0 = b * 512 + kt * 64;
#pragma unroll
        for (int p = 0; p < 4; ++p) {
            int ch = t + 256 * p;
            int r = ch >> 4;
            int col = (ch & 15) * 8;
            const u16* src = (col < 64)
                ? kv_src + (size_t)(krow0 + r) * 2048 + h * 64 + col
                : kr_src + (size_t)(krow0 + r) * 1088 + 1024 + (col - 64);
            *(uint4*)&Ks[r * 136 + col] = *(const uint4*)src;
        }
#pragma unroll
        for (int p = 0; p < 2; ++p) {
            int ch = t + 256 * p;
            int r = ch >> 3;            // key row 0..63
            int v0 = (ch & 7) * 8;      // vd chunk
            uint4 vv = *(const uint4*)(kv_src + (size_t)(krow0 + r) * 2048 + 1024 + h * 64 + v0);
            u16 tmp[8];
            __builtin_memcpy(tmp, &vv, 16);
#pragma unroll
            for (int j2 = 0; j2 < 8; ++j2)
                Vt[(v0 + j2) * 72 + r] = tmp[j2];
        }
        __syncthreads();

        // S strip = Q K^T  (16 q rows x 64 keys), contraction d=128
        f32x4 s[4];
#pragma unroll
        for (int n = 0; n < 4; ++n) s[n] = (f32x4){0.f, 0.f, 0.f, 0.f};
#pragma unroll
        for (int ks = 0; ks < 4; ++ks) {
            bf16x8 aq = *(const bf16x8*)&Qs[(w * 16 + l16) * 136 + ks * 32 + quad * 8];
#pragma unroll
            for (int n = 0; n < 4; ++n) {
                bf16x8 bk = *(const bf16x8*)&Ks[(n * 16 + l16) * 136 + ks * 32 + quad * 8];
                s[n] = __builtin_amdgcn_mfma_f32_16x16x32_bf16(aq, bk, s[n], 0, 0, 0);
            }
        }

        // online softmax; lane owns rows quad*4+r, cols l16 (+16n)
        float mx[4], alpha[4], rs[4];
#pragma unroll
        for (int r = 0; r < 4; ++r) {
#pragma unroll
            for (int n = 0; n < 4; ++n) s[n][r] *= scale;
            mx[r] = fmaxf(fmaxf(s[0][r], s[1][r]), fmaxf(s[2][r], s[3][r]));
        }
#pragma unroll
        for (int d = 1; d < 16; d <<= 1)
#pragma unroll
            for (int r = 0; r < 4; ++r)
                mx[r] = fmaxf(mx[r], __shfl_xor(mx[r], d));
#pragma unroll
        for (int r = 0; r < 4; ++r) {
            float mnew = fmaxf(m_run[r], mx[r]);
            alpha[r] = __expf(m_run[r] - mnew);
            m_run[r] = mnew;
            rs[r] = 0.f;
#pragma unroll
            for (int n = 0; n < 4; ++n) {
                float pv = __expf(s[n][r] - mnew);
                s[n][r] = pv;
                rs[r] += pv;
            }
        }
#pragma unroll
        for (int d = 1; d < 16; d <<= 1)
#pragma unroll
            for (int r = 0; r < 4; ++r)
                rs[r] += __shfl_xor(rs[r], d);
#pragma unroll
        for (int r = 0; r < 4; ++r) {
            l_run[r] = l_run[r] * alpha[r] + rs[r];
#pragma unroll
            for (int n = 0; n < 4; ++n) o[n][r] *= alpha[r];
        }

        // P: C-layout -> LDS (wave-private 16-row strip)
#pragma unroll
        for (int n = 0; n < 4; ++n)
#pragma unroll
            for (int r = 0; r < 4; ++r)
                Ps[(w * 16 + quad * 4 + r) * 72 + n * 16 + l16] = f2bf(s[n][r]);
        __syncthreads();

        // O += P @ V   (contraction over 64 keys)
#pragma unroll
        for (int kk = 0; kk < 2; ++kk) {
            bf16x8 ap = *(const bf16x8*)&Ps[(w * 16 + l16) * 72 + kk * 32 + quad * 8];
#pragma unroll
            for (int n = 0; n < 4; ++n) {
                bf16x8 bv = *(const bf16x8*)&Vt[(n * 16 + l16) * 72 + kk * 32 + quad * 8];
                o[n] = __builtin_amdgcn_mfma_f32_16x16x32_bf16(ap, bv, o[n], 0, 0, 0);
            }
        }
    }

#pragma unroll
    for (int n = 0; n < 4; ++n) {
#pragma unroll
        for (int r = 0; r < 4; ++r) {
            int row = qrow0 + w * 16 + quad * 4 + r;
            int col = h * 64 + n * 16 + l16;
            o_dst[(size_t)row * ldo + col] = f2bf(o[n][r] / l_run[r]);
        }
    }
}

// ---------------------------------------------------------------------------
extern "C" void kernel_launch(void* const* d_in, const int* in_sizes, int n_in,
                              void* d_out, int out_size, void* d_ws, size_t ws_size,
                              hipStream_t stream)
{
    // All reference dtypes are float32.
    const float* h    = (const float*)d_in[0];
    const float* Wdkv = (const float*)d_in[1];
    const float* bdkv = (const float*)d_in[2];
    const float* Wuk  = (const float*)d_in[3];
    const float* buk  = (const float*)d_in[4];
    const float* Wuv  = (const float*)d_in[5];
    const float* buv  = (const float*)d_in[6];
    const float* Wdq  = (const float*)d_in[7];
    const float* bdq  = (const float*)d_in[8];
    const float* Wuq  = (const float*)d_in[9];
    const float* buq  = (const float*)d_in[10];
    const float* Wqr  = (const float*)d_in[11];
    const float* bqr  = (const float*)d_in[12];
    const float* Wkr  = (const float*)d_in[13];
    const float* bkr  = (const float*)d_in[14];
    const float* Wfc  = (const float*)d_in[15];
    const float* bfc  = (const float*)d_in[16];

    // Workspace (bf16 intermediates): 84,934,656 bytes total.
    //   out1 : 8192 x 1088  [c_kv | c_q | k_r]; attn output reuses cols 0..1023
    //   out2a: 8192 x 2048  [k_c | v_c]
    //   out2b: 8192 x 2048  [q_c | q_r]
    char* ws = (char*)d_ws;
    u16* out1  = (u16*)ws;                          // 17,825,792 B
    u16* out2a = (u16*)(ws + 17825792);             // 33,554,432 B
    u16* out2b = (u16*)(ws + 17825792 + 33554432);  // 33,554,432 B

    // stage 1: from h fp32 (K=2048), weights fp32 -> bf16 ws
    gemm_bt<true,true,false><<<dim3(64, 4), 256, 0, stream>>>(h, 2048, Wdkv, 2048, out1,        1088, 512,  2048, bdkv);
    gemm_bt<true,true,false><<<dim3(64, 4), 256, 0, stream>>>(h, 2048, Wdq,  2048, out1 + 512,  1088, 512,  2048, bdq);
    gemm_bt<true,true,false><<<dim3(64, 1), 256, 0, stream>>>(h, 2048, Wkr,  2048, out1 + 1024, 1088, 64,   2048, bkr);
    rope_inplace<<<1024, 256, 0, stream>>>(out1, 1088, 1024, 32, 8192 * 32);   // k_r

    // stage 2: A = bf16 ws, B = fp32 weights (K=512)
    gemm_bt<false,true,false><<<dim3(64, 8), 256, 0, stream>>>(out1,       1088, Wuk, 512, out2a,        2048, 1024, 512, buk);
    gemm_bt<false,true,false><<<dim3(64, 8), 256, 0, stream>>>(out1,       1088, Wuv, 512, out2a + 1024, 2048, 1024, 512, buv);
    gemm_bt<false,true,false><<<dim3(64, 8), 256, 0, stream>>>(out1 + 512, 1088, Wuq, 512, out2b,        2048, 1024, 512, buq);
    gemm_bt<false,true,false><<<dim3(64, 8), 256, 0, stream>>>(out1 + 512, 1088, Wqr, 512, out2b + 1024, 2048, 1024, 512, bqr);
    rope_inplace<<<16384, 256, 0, stream>>>(out2b, 2048, 1024, 512, 8192 * 512);  // q_r

    // attention: output overwrites out1 cols 0..1023 (c_kv/c_q, now dead)
    attn_kernel<<<dim3(8, 16, 16), 256, 0, stream>>>(out2b, out2a, out1, out1, 1088);

    // final projection: A = attn out (bf16, lda=1088, K=1024), C = fp32 d_out
    gemm_bt<false,true,true><<<dim3(64, 16), 256, 0, stream>>>(out1, 1088, Wfc, 1024, d_out, 2048, 2048, 1024, bfc);
}

// Round 4
// 672.165 us; speedup vs baseline: 1.3851x; 1.3851x over previous
//
#include <hip/hip_runtime.h>
#include <hip/hip_bf16.h>

typedef __bf16 bf16x8 __attribute__((ext_vector_type(8)));
typedef float f32x4 __attribute__((ext_vector_type(4)));
using u16 = unsigned short;
using u32 = unsigned int;

__device__ __forceinline__ float bf2f(u16 v) {
    unsigned int u = (unsigned int)v << 16;
    float f; __builtin_memcpy(&f, &u, 4); return f;
}
__device__ __forceinline__ u16 f2bf(float f) {
    unsigned int u; __builtin_memcpy(&u, &f, 4);
    u += 0x7FFFu + ((u >> 16) & 1u);   // RNE (finite data only)
    return (u16)(u >> 16);
}

// ---------------------------------------------------------------------------
// Fused C = A @ [B0;B1;B2]^T + [bias0;bias1;bias2] GEMM.
//  A: M x K.  ABF16 ? bf16 staged via global_load_lds (unpadded LDS stride 32,
//  XOR chunk swizzle so b128 fragment reads stay 2-way on banks)
//             : fp32 staged via VGPR cvt + ds_write (padded LDS stride 40).
//  B: fp32 weight rows; section n of [0,s0) -> B0, [s0,s1) -> B1, else B2.
//  128x128 tile, BK=32, 4 waves, 4x4 grid of 16x16x32 bf16 MFMA per wave.
//  M multiple of 128; N multiple of 16; sections multiples of 128.
// ---------------------------------------------------------------------------
template<bool ABF16, bool CF>
__global__ __launch_bounds__(256) void gemm_v2(
    const void* __restrict__ Av, int lda,
    const float* __restrict__ B0, const float* __restrict__ B1, const float* __restrict__ B2,
    int s0, int s1, int ldb,
    void* __restrict__ Cv, int ldc, int N, int K,
    const float* __restrict__ bias0, const float* __restrict__ bias1, const float* __restrict__ bias2)
{
    constexpr int ASTR = ABF16 ? 32 : 40;
    __shared__ __align__(16) u16 As[128 * ASTR];
    __shared__ __align__(16) u16 Bs[128 * 40];

    const int t = threadIdx.x;
    const int lane = t & 63;
    const int w = t >> 6;
    const int wm = w >> 1, wn = w & 1;
    const int l16 = lane & 15, quad = lane >> 4;
    const int m0 = blockIdx.x * 128;
    const int n0 = blockIdx.y * 128;

    // tile-uniform weight-section selection
    const float* Bsel; int nrel;
    if (n0 < s0)      { Bsel = B0; nrel = n0; }
    else if (n0 < s1) { Bsel = B1; nrel = n0 - s0; }
    else              { Bsel = B2; nrel = n0 - s1; }

    const int sub  = lane >> 2;                    // 0..15 (row within 16-row chunk)
    const int slot = lane & 3;                     // 16B slot within 64B row
    const int agc  = ABF16 ? (slot ^ ((sub >> 1) & 3)) : slot;  // A global chunk (swizzled)
    const int sfr  = (l16 >> 1) & 3;               // fragment-read swizzle

    f32x4 acc[4][4];
#pragma unroll
    for (int i = 0; i < 4; ++i)
#pragma unroll
        for (int j = 0; j < 4; ++j) acc[i][j] = (f32x4){0.f, 0.f, 0.f, 0.f};

    for (int k0 = 0; k0 < K; k0 += 32) {
        __syncthreads();
#pragma unroll
        for (int c = 0; c < 2; ++c) {
            const int row = w * 32 + c * 16 + sub;
            // ---- A staging ----
            if (ABF16) {
                const u16* ga = (const u16*)Av + (size_t)(m0 + row) * lda + k0 + agc * 8;
                __builtin_amdgcn_global_load_lds(
                    (const __attribute__((address_space(1))) u32*)ga,
                    (__attribute__((address_space(3))) u32*)&As[(w * 32 + c * 16) * 32],
                    16, 0, 0);
            } else {
                const float* ap = (const float*)Av + (size_t)(m0 + row) * lda + k0 + slot * 8;
                float4 f0 = *(const float4*)ap;
                float4 f1 = *(const float4*)(ap + 4);
                u16 tmp[8] = { f2bf(f0.x), f2bf(f0.y), f2bf(f0.z), f2bf(f0.w),
                               f2bf(f1.x), f2bf(f1.y), f2bf(f1.z), f2bf(f1.w) };
                *(uint4*)&As[row * 40 + slot * 8] = *(const uint4*)tmp;
            }
            // ---- B staging (fp32 manual, N-guarded; guard is chunk-aligned) ----
            int gn = n0 + row;
            u16 tb[8] = {0,0,0,0,0,0,0,0};
            if (gn < N) {
                const float* bp = Bsel + (size_t)(nrel + row) * ldb + k0 + slot * 8;
                float4 f0 = *(const float4*)bp;
                float4 f1 = *(const float4*)(bp + 4);
                tb[0]=f2bf(f0.x); tb[1]=f2bf(f0.y); tb[2]=f2bf(f0.z); tb[3]=f2bf(f0.w);
                tb[4]=f2bf(f1.x); tb[5]=f2bf(f1.y); tb[6]=f2bf(f1.z); tb[7]=f2bf(f1.w);
            }
            *(uint4*)&Bs[row * 40 + slot * 8] = *(const uint4*)tb;
        }
        __syncthreads();

        bf16x8 af[4], bfr[4];
#pragma unroll
        for (int i = 0; i < 4; ++i) {
            int r = wm * 64 + i * 16 + l16;
            if (ABF16) af[i] = *(const bf16x8*)&As[r * 32 + (quad ^ sfr) * 8];
            else       af[i] = *(const bf16x8*)&As[r * 40 + quad * 8];
        }
#pragma unroll
        for (int j = 0; j < 4; ++j)
            bfr[j] = *(const bf16x8*)&Bs[(wn * 64 + j * 16 + l16) * 40 + quad * 8];
#pragma unroll
        for (int i = 0; i < 4; ++i)
#pragma unroll
            for (int j = 0; j < 4; ++j)
                acc[i][j] = __builtin_amdgcn_mfma_f32_16x16x32_bf16(af[i], bfr[j], acc[i][j], 0, 0, 0);
    }

#pragma unroll
    for (int j = 0; j < 4; ++j) {
        int col = n0 + wn * 64 + j * 16 + l16;
        if (col >= N) continue;
        float bv;
        if (col < s0)      bv = bias0[col];
        else if (col < s1) bv = bias1[col - s0];
        else               bv = bias2[col - s1];
#pragma unroll
        for (int i = 0; i < 4; ++i) {
#pragma unroll
            for (int r = 0; r < 4; ++r) {
                int row = m0 + wm * 64 + i * 16 + quad * 4 + r;
                float v = acc[i][j][r] + bv;
                if (CF) ((float*)Cv)[(size_t)row * ldc + col] = v;
                else    ((u16*)Cv)[(size_t)row * ldc + col] = f2bf(v);
            }
        }
    }
}

// ---------------------------------------------------------------------------
// RoPE in place on bf16 ws buffers, faithful to the source quirk (cos_pos =
// sin(ang), sin_pos = cos(ang)):  out[2i] = x[2i]*sin - x[2i+1]*cos ;
// out[2i+1] = x[2i+1]*sin + x[2i]*cos ;  ang = (row % 512) * 10000^(-i/32).
// ---------------------------------------------------------------------------
__global__ void rope_inplace(u16* __restrict__ buf, int ld, int col0, int ppr, int total)
{
    int idx = blockIdx.x * 256 + threadIdx.x;
    if (idx >= total) return;
    int row = idx / ppr;
    int pi  = idx - row * ppr;
    int grp = pi >> 5;
    int i   = pi & 31;
    int pos = row & 511;
    float theta = __expf(-(float)i * 0.2878231366242558f);  // ln(10000)/32
    float ang = (float)pos * theta;
    float s = sinf(ang), c = cosf(ang);
    size_t base = (size_t)row * ld + col0 + grp * 64 + 2 * i;
    float x0 = bf2f(buf[base]);
    float x1 = bf2f(buf[base + 1]);
    buf[base]     = f2bf(x0 * s - x1 * c);
    buf[base + 1] = f2bf(x1 * s + x0 * c);
}

// ---------------------------------------------------------------------------
// Flash attention (all operands bf16 in ws).  One WG = (b, h, 64-row q tile),
// 4 waves; wave w owns a 16-row q strip.  64-key tiles, online softmax,
// P: C-layout -> LDS -> A-layout; V staged transposed for b128 b-frags.
// Output into o_dst cols 0..1023 (aliases out1's dead c_kv/c_q region; this
// kernel only READS out1 cols 1024..1087, byte-disjoint from the writes).
// ---------------------------------------------------------------------------
__global__ __launch_bounds__(256) void attn_kernel(
    const u16* __restrict__ q_src,   // 8192 x 2048 : [q_c | q_r(roped)]
    const u16* __restrict__ kv_src,  // 8192 x 2048 : [k_c | v_c]
    const u16* __restrict__ kr_src,  // 8192 x 1088 : k_r at col 1024 (roped)
    u16* __restrict__ o_dst, int ldo)
{
    __shared__ __align__(16) u16 Qs[64 * 136];
    __shared__ __align__(16) u16 Ks[64 * 136];
    __shared__ __align__(16) u16 Vt[64 * 72];   // [vd][key]
    __shared__ __align__(16) u16 Ps[64 * 72];   // [q][key]

    const int t = threadIdx.x;
    const int lane = t & 63;
    const int w = t >> 6;
    const int l16 = lane & 15, quad = lane >> 4;
    const int qt = blockIdx.x;   // 0..7
    const int h  = blockIdx.y;   // 0..15
    const int b  = blockIdx.z;   // 0..15
    const int qrow0 = b * 512 + qt * 64;

    // Q tile: 64 x 128 = [q_c | q_r]
#pragma unroll
    for (int p = 0; p < 4; ++p) {
        int ch = t + 256 * p;
        int r = ch >> 4;
        int col = (ch & 15) * 8;
        const u16* src = (col < 64)
            ? q_src + (size_t)(qrow0 + r) * 2048 + h * 64 + col
            : q_src + (size_t)(qrow0 + r) * 2048 + 1024 + h * 64 + (col - 64);
        *(uint4*)&Qs[r * 136 + col] = *(const uint4*)src;
    }

    float m_run[4], l_run[4];
    f32x4 o[4];
#pragma unroll
    for (int r = 0; r < 4; ++r) { m_run[r] = -1e30f; l_run[r] = 0.f; }
#pragma unroll
    for (int n = 0; n < 4; ++n) o[n] = (f32x4){0.f, 0.f, 0.f, 0.f};

    const float scale = 0.07216878364870323f;  // 1/sqrt(192)

    for (int kt = 0; kt < 8; ++kt) {
        __syncthreads();  // prev iter done with Ks/Vt/Ps; also orders Q staging
        const int krow0 = b * 512 + kt * 64;
#pragma unroll
        for (int p = 0; p < 4; ++p) {
            int ch = t + 256 * p;
            int r = ch >> 4;
            int col = (ch & 15) * 8;
            const u16* src = (col < 64)
                ? kv_src + (size_t)(krow0 + r) * 2048 + h * 64 + col
                : kr_src + (size_t)(krow0 + r) * 1088 + 1024 + (col - 64);
            *(uint4*)&Ks[r * 136 + col] = *(const uint4*)src;
        }
#pragma unroll
        for (int p = 0; p < 2; ++p) {
            int ch = t + 256 * p;
            int r = ch >> 3;            // key row 0..63
            int v0 = (ch & 7) * 8;      // vd chunk
            uint4 vv = *(const uint4*)(kv_src + (size_t)(krow0 + r) * 2048 + 1024 + h * 64 + v0);
            u16 tmp[8];
            __builtin_memcpy(tmp, &vv, 16);
#pragma unroll
            for (int j2 = 0; j2 < 8; ++j2)
                Vt[(v0 + j2) * 72 + r] = tmp[j2];
        }
        __syncthreads();

        // S strip = Q K^T  (16 q rows x 64 keys), contraction d=128
        f32x4 s[4];
#pragma unroll
        for (int n = 0; n < 4; ++n) s[n] = (f32x4){0.f, 0.f, 0.f, 0.f};
#pragma unroll
        for (int ks = 0; ks < 4; ++ks) {
            bf16x8 aq = *(const bf16x8*)&Qs[(w * 16 + l16) * 136 + ks * 32 + quad * 8];
#pragma unroll
            for (int n = 0; n < 4; ++n) {
                bf16x8 bk = *(const bf16x8*)&Ks[(n * 16 + l16) * 136 + ks * 32 + quad * 8];
                s[n] = __builtin_amdgcn_mfma_f32_16x16x32_bf16(aq, bk, s[n], 0, 0, 0);
            }
        }

        // online softmax; lane owns rows quad*4+r, cols l16 (+16n)
        float mx[4], alpha[4], rs[4];
#pragma unroll
        for (int r = 0; r < 4; ++r) {
#pragma unroll
            for (int n = 0; n < 4; ++n) s[n][r] *= scale;
            mx[r] = fmaxf(fmaxf(s[0][r], s[1][r]), fmaxf(s[2][r], s[3][r]));
        }
#pragma unroll
        for (int d = 1; d < 16; d <<= 1)
#pragma unroll
            for (int r = 0; r < 4; ++r)
                mx[r] = fmaxf(mx[r], __shfl_xor(mx[r], d));
#pragma unroll
        for (int r = 0; r < 4; ++r) {
            float mnew = fmaxf(m_run[r], mx[r]);
            alpha[r] = __expf(m_run[r] - mnew);
            m_run[r] = mnew;
            rs[r] = 0.f;
#pragma unroll
            for (int n = 0; n < 4; ++n) {
                float pv = __expf(s[n][r] - mnew);
                s[n][r] = pv;
                rs[r] += pv;
            }
        }
#pragma unroll
        for (int d = 1; d < 16; d <<= 1)
#pragma unroll
            for (int r = 0; r < 4; ++r)
                rs[r] += __shfl_xor(rs[r], d);
#pragma unroll
        for (int r = 0; r < 4; ++r) {
            l_run[r] = l_run[r] * alpha[r] + rs[r];
#pragma unroll
            for (int n = 0; n < 4; ++n) o[n][r] *= alpha[r];
        }

        // P: C-layout -> LDS (wave-private 16-row strip)
#pragma unroll
        for (int n = 0; n < 4; ++n)
#pragma unroll
            for (int r = 0; r < 4; ++r)
                Ps[(w * 16 + quad * 4 + r) * 72 + n * 16 + l16] = f2bf(s[n][r]);
        __syncthreads();

        // O += P @ V   (contraction over 64 keys)
#pragma unroll
        for (int kk = 0; kk < 2; ++kk) {
            bf16x8 ap = *(const bf16x8*)&Ps[(w * 16 + l16) * 72 + kk * 32 + quad * 8];
#pragma unroll
            for (int n = 0; n < 4; ++n) {
                bf16x8 bv = *(const bf16x8*)&Vt[(n * 16 + l16) * 72 + kk * 32 + quad * 8];
                o[n] = __builtin_amdgcn_mfma_f32_16x16x32_bf16(ap, bv, o[n], 0, 0, 0);
            }
        }
    }

#pragma unroll
    for (int n = 0; n < 4; ++n) {
#pragma unroll
        for (int r = 0; r < 4; ++r) {
            int row = qrow0 + w * 16 + quad * 4 + r;
            int col = h * 64 + n * 16 + l16;
            o_dst[(size_t)row * ldo + col] = f2bf(o[n][r] / l_run[r]);
        }
    }
}

// ---------------------------------------------------------------------------
extern "C" void kernel_launch(void* const* d_in, const int* in_sizes, int n_in,
                              void* d_out, int out_size, void* d_ws, size_t ws_size,
                              hipStream_t stream)
{
    // All reference dtypes are float32.
    const float* h    = (const float*)d_in[0];
    const float* Wdkv = (const float*)d_in[1];
    const float* bdkv = (const float*)d_in[2];
    const float* Wuk  = (const float*)d_in[3];
    const float* buk  = (const float*)d_in[4];
    const float* Wuv  = (const float*)d_in[5];
    const float* buv  = (const float*)d_in[6];
    const float* Wdq  = (const float*)d_in[7];
    const float* bdq  = (const float*)d_in[8];
    const float* Wuq  = (const float*)d_in[9];
    const float* buq  = (const float*)d_in[10];
    const float* Wqr  = (const float*)d_in[11];
    const float* bqr  = (const float*)d_in[12];
    const float* Wkr  = (const float*)d_in[13];
    const float* bkr  = (const float*)d_in[14];
    const float* Wfc  = (const float*)d_in[15];
    const float* bfc  = (const float*)d_in[16];

    // Workspace (bf16 intermediates): 84,934,656 bytes (known-good size).
    //   out1 : 8192 x 1088  [c_kv | c_q | k_r]; attn output reuses cols 0..1023
    //   out2a: 8192 x 2048  [k_c | v_c]
    //   out2b: 8192 x 2048  [q_c | q_r]
    char* ws = (char*)d_ws;
    u16* out1  = (u16*)ws;                          // 17,825,792 B
    u16* out2a = (u16*)(ws + 17825792);             // 33,554,432 B
    u16* out2b = (u16*)(ws + 17825792 + 33554432);  // 33,554,432 B

    // stage 1 (fused): [c_kv | c_q | k_r] = h @ [Wdkv;Wdq;Wkr]^T, N=1088, K=2048
    gemm_v2<false,false><<<dim3(64, 9), 256, 0, stream>>>(
        h, 2048, Wdkv, Wdq, Wkr, 512, 1024, 2048,
        out1, 1088, 1088, 2048, bdkv, bdq, bkr);
    rope_inplace<<<1024, 256, 0, stream>>>(out1, 1088, 1024, 32, 8192 * 32);   // k_r

    // stage 2a (fused): [k_c | v_c] = c_kv @ [Wuk;Wuv]^T, N=2048, K=512
    gemm_v2<true,false><<<dim3(64, 16), 256, 0, stream>>>(
        out1, 1088, Wuk, Wuv, nullptr, 1024, 2048, 512,
        out2a, 2048, 2048, 512, buk, buv, nullptr);
    // stage 2b (fused): [q_c | q_r] = c_q @ [Wuq;Wqr]^T, N=2048, K=512
    gemm_v2<true,false><<<dim3(64, 16), 256, 0, stream>>>(
        out1 + 512, 1088, Wuq, Wqr, nullptr, 1024, 2048, 512,
        out2b, 2048, 2048, 512, buq, bqr, nullptr);
    rope_inplace<<<16384, 256, 0, stream>>>(out2b, 2048, 1024, 512, 8192 * 512);  // q_r

    // attention: output overwrites out1 cols 0..1023 (c_kv/c_q, now dead)
    attn_kernel<<<dim3(8, 16, 16), 256, 0, stream>>>(out2b, out2a, out1, out1, 1088);

    // final projection: A = attn out (bf16, lda=1088, K=1024), C = fp32 d_out
    gemm_v2<true,true><<<dim3(64, 16), 256, 0, stream>>>(
        out1, 1088, Wfc, nullptr, nullptr, 2048, 4096, 1024,
        d_out, 2048, 2048, 1024, bfc, nullptr, nullptr);
}

// Round 5
// 475.785 us; speedup vs baseline: 1.9568x; 1.4127x over previous
//
#include <hip/hip_runtime.h>
#include <hip/hip_bf16.h>

typedef __bf16 bf16x8 __attribute__((ext_vector_type(8)));
typedef float f32x4 __attribute__((ext_vector_type(4)));
using u16 = unsigned short;
using u32 = unsigned int;

__device__ __forceinline__ float bf2f(u16 v) {
    unsigned int u = (unsigned int)v << 16;
    float f; __builtin_memcpy(&f, &u, 4); return f;
}
__device__ __forceinline__ u16 f2bf(float f) {
    unsigned int u; __builtin_memcpy(&u, &f, 4);
    u += 0x7FFFu + ((u >> 16) & 1u);   // RNE (finite data only)
    return (u16)(u >> 16);
}

// ---------------------------------------------------------------------------
// Bulk fp32 -> bf16 conversion, 9 segments, 8 elems/thread.
// ---------------------------------------------------------------------------
struct Cvt9 {
    const float* src[9];
    u16* dst[9];
    int end[9];      // cumulative chunk ends (chunks of 8 elems)
};
__global__ __launch_bounds__(256) void cvt_all(Cvt9 d, int total)
{
    int c = blockIdx.x * 256 + threadIdx.x;
    if (c >= total) return;
    int seg = 0;
    while (c >= d.end[seg]) ++seg;
    int local = c - (seg ? d.end[seg - 1] : 0);
    const float* s = d.src[seg] + (size_t)local * 8;
    float4 f0 = *(const float4*)s;
    float4 f1 = *(const float4*)(s + 4);
    u16 tmp[8] = { f2bf(f0.x), f2bf(f0.y), f2bf(f0.z), f2bf(f0.w),
                   f2bf(f1.x), f2bf(f1.y), f2bf(f1.z), f2bf(f1.w) };
    *(uint4*)(d.dst[seg] + (size_t)local * 8) = *(const uint4*)tmp;
}

// ---------------------------------------------------------------------------
// Bias concatenation (fp32 copy, 7 segments).
// ---------------------------------------------------------------------------
struct Cpy7 {
    const float* src[7];
    float* dst[7];
    int end[7];
};
__global__ __launch_bounds__(256) void copy_f32(Cpy7 d, int total)
{
    int c = blockIdx.x * 256 + threadIdx.x;
    if (c >= total) return;
    int seg = 0;
    while (c >= d.end[seg]) ++seg;
    int local = c - (seg ? d.end[seg - 1] : 0);
    d.dst[seg][local] = d.src[seg][local];
}

// ---------------------------------------------------------------------------
// Pure-bf16 C = A @ B^T + bias GEMM, two independent "halves" selected by
// blockIdx.y < ysplit (for fusing two GEMMs of identical dims in one grid).
// A: M x K bf16 (lda), B: N x K bf16 (ldb) with rows padded to a multiple of
// 128 (pad rows zero).  Both operands staged via global_load_lds width=16
// into unpadded LDS (stride 32 elems) with XOR chunk swizzle; fragment reads
// are b128, 2-way bank aliasing (free).  128x128 tile, BK=32, 4 waves, 4x4
// grid of 16x16x32 bf16 MFMA/wave.  M mult of 128; epilogue guards col < N.
// ---------------------------------------------------------------------------
template<bool CF>
__global__ __launch_bounds__(256) void gemm_v3(
    const u16* __restrict__ A0, const u16* __restrict__ B0, void* __restrict__ C0, const float* __restrict__ e0,
    const u16* __restrict__ A1, const u16* __restrict__ B1, void* __restrict__ C1, const float* __restrict__ e1,
    int ysplit, int lda, int ldb, int ldc, int N, int K)
{
    __shared__ __align__(16) u16 As[128 * 32];
    __shared__ __align__(16) u16 Bs[128 * 32];

    const int t = threadIdx.x;
    const int lane = t & 63;
    const int w = t >> 6;
    const int wm = w >> 1, wn = w & 1;
    const int l16 = lane & 15, quad = lane >> 4;
    const int m0 = blockIdx.x * 128;

    const u16* A; const u16* B; void* Cv; const float* bias; int yl;
    if ((int)blockIdx.y < ysplit) { A = A0; B = B0; Cv = C0; bias = e0; yl = blockIdx.y; }
    else                          { A = A1; B = B1; Cv = C1; bias = e1; yl = blockIdx.y - ysplit; }
    const int n0 = yl * 128;

    const int sub  = lane >> 2;                 // 0..15: row within 16-row chunk
    const int slot = lane & 3;                  // 16B slot within 64B row
    const int agc  = slot ^ ((sub >> 1) & 3);   // swizzled global chunk
    const int sfr  = (l16 >> 1) & 3;            // fragment-read unswizzle

    f32x4 acc[4][4];
#pragma unroll
    for (int i = 0; i < 4; ++i)
#pragma unroll
        for (int j = 0; j < 4; ++j) acc[i][j] = (f32x4){0.f, 0.f, 0.f, 0.f};

    for (int k0 = 0; k0 < K; k0 += 32) {
        __syncthreads();
#pragma unroll
        for (int c = 0; c < 2; ++c) {
            const int rr = w * 32 + c * 16;
            const u16* ga = A + (size_t)(m0 + rr + sub) * lda + k0 + agc * 8;
            __builtin_amdgcn_global_load_lds(
                (const __attribute__((address_space(1))) u32*)ga,
                (__attribute__((address_space(3))) u32*)&As[rr * 32], 16, 0, 0);
            const u16* gb = B + (size_t)(n0 + rr + sub) * ldb + k0 + agc * 8;
            __builtin_amdgcn_global_load_lds(
                (const __attribute__((address_space(1))) u32*)gb,
                (__attribute__((address_space(3))) u32*)&Bs[rr * 32], 16, 0, 0);
        }
        __syncthreads();

        bf16x8 af[4], bfr[4];
#pragma unroll
        for (int i = 0; i < 4; ++i)
            af[i] = *(const bf16x8*)&As[(wm * 64 + i * 16 + l16) * 32 + (quad ^ sfr) * 8];
#pragma unroll
        for (int j = 0; j < 4; ++j)
            bfr[j] = *(const bf16x8*)&Bs[(wn * 64 + j * 16 + l16) * 32 + (quad ^ sfr) * 8];
#pragma unroll
        for (int i = 0; i < 4; ++i)
#pragma unroll
            for (int j = 0; j < 4; ++j)
                acc[i][j] = __builtin_amdgcn_mfma_f32_16x16x32_bf16(af[i], bfr[j], acc[i][j], 0, 0, 0);
    }

#pragma unroll
    for (int j = 0; j < 4; ++j) {
        int col = n0 + wn * 64 + j * 16 + l16;
        if (col >= N) continue;
        float bv = bias[col];
#pragma unroll
        for (int i = 0; i < 4; ++i) {
#pragma unroll
            for (int r = 0; r < 4; ++r) {
                int row = m0 + wm * 64 + i * 16 + quad * 4 + r;
                float v = acc[i][j][r] + bv;
                if (CF) ((float*)Cv)[(size_t)row * ldc + col] = v;
                else    ((u16*)Cv)[(size_t)row * ldc + col] = f2bf(v);
            }
        }
    }
}

// ---------------------------------------------------------------------------
// RoPE in place on bf16 ws buffers (source quirk: cos_pos = sin, sin_pos =
// cos):  out[2i] = x[2i]*sin - x[2i+1]*cos ; out[2i+1] = x[2i+1]*sin +
// x[2i]*cos ;  ang = (row % 512) * 10000^(-i/32).
// ---------------------------------------------------------------------------
__global__ void rope_inplace(u16* __restrict__ buf, int ld, int col0, int ppr, int total)
{
    int idx = blockIdx.x * 256 + threadIdx.x;
    if (idx >= total) return;
    int row = idx / ppr;
    int pi  = idx - row * ppr;
    int grp = pi >> 5;
    int i   = pi & 31;
    int pos = row & 511;
    float theta = __expf(-(float)i * 0.2878231366242558f);  // ln(10000)/32
    float ang = (float)pos * theta;
    float s = sinf(ang), c = cosf(ang);
    size_t base = (size_t)row * ld + col0 + grp * 64 + 2 * i;
    float x0 = bf2f(buf[base]);
    float x1 = bf2f(buf[base + 1]);
    buf[base]     = f2bf(x0 * s - x1 * c);
    buf[base + 1] = f2bf(x1 * s + x0 * c);
}

// ---------------------------------------------------------------------------
// Flash attention (all operands bf16 in ws).  One WG = (b, h, 64-row q tile),
// 4 waves; wave w owns a 16-row q strip.  64-key tiles, online softmax,
// P: C-layout -> LDS -> A-layout; V staged transposed for b128 b-frags.
// Output into o_dst cols 0..1023 (aliases out1's dead c_kv/c_q region; this
// kernel only READS out1 cols 1024..1087, byte-disjoint from the writes).
// ---------------------------------------------------------------------------
__global__ __launch_bounds__(256) void attn_kernel(
    const u16* __restrict__ q_src,   // 8192 x 2048 : [q_c | q_r(roped)]
    const u16* __restrict__ kv_src,  // 8192 x 2048 : [k_c | v_c]
    const u16* __restrict__ kr_src,  // 8192 x 1088 : k_r at col 1024 (roped)
    u16* __restrict__ o_dst, int ldo)
{
    __shared__ __align__(16) u16 Qs[64 * 136];
    __shared__ __align__(16) u16 Ks[64 * 136];
    __shared__ __align__(16) u16 Vt[64 * 72];   // [vd][key]
    __shared__ __align__(16) u16 Ps[64 * 72];   // [q][key]

    const int t = threadIdx.x;
    const int lane = t & 63;
    const int w = t >> 6;
    const int l16 = lane & 15, quad = lane >> 4;
    const int qt = blockIdx.x;   // 0..7
    const int h  = blockIdx.y;   // 0..15
    const int b  = blockIdx.z;   // 0..15
    const int qrow0 = b * 512 + qt * 64;

    // Q tile: 64 x 128 = [q_c | q_r]
#pragma unroll
    for (int p = 0; p < 4; ++p) {
        int ch = t + 256 * p;
        int r = ch >> 4;
        int col = (ch & 15) * 8;
        const u16* src = (col < 64)
            ? q_src + (size_t)(qrow0 + r) * 2048 + h * 64 + col
            : q_src + (size_t)(qrow0 + r) * 2048 + 1024 + h * 64 + (col - 64);
        *(uint4*)&Qs[r * 136 + col] = *(const uint4*)src;
    }

    float m_run[4], l_run[4];
    f32x4 o[4];
#pragma unroll
    for (int r = 0; r < 4; ++r) { m_run[r] = -1e30f; l_run[r] = 0.f; }
#pragma unroll
    for (int n = 0; n < 4; ++n) o[n] = (f32x4){0.f, 0.f, 0.f, 0.f};

    const float scale = 0.07216878364870323f;  // 1/sqrt(192)

    for (int kt = 0; kt < 8; ++kt) {
        __syncthreads();  // prev iter done with Ks/Vt/Ps; also orders Q staging
        const int krow0 = b * 512 + kt * 64;
#pragma unroll
        for (int p = 0; p < 4; ++p) {
            int ch = t + 256 * p;
            int r = ch >> 4;
            int col = (ch & 15) * 8;
            const u16* src = (col < 64)
                ? kv_src + (size_t)(krow0 + r) * 2048 + h * 64 + col
                : kr_src + (size_t)(krow0 + r) * 1088 + 1024 + (col - 64);
            *(uint4*)&Ks[r * 136 + col] = *(const uint4*)src;
        }
#pragma unroll
        for (int p = 0; p < 2; ++p) {
            int ch = t + 256 * p;
            int r = ch >> 3;            // key row 0..63
            int v0 = (ch & 7) * 8;      // vd chunk
            uint4 vv = *(const uint4*)(kv_src + (size_t)(krow0 + r) * 2048 + 1024 + h * 64 + v0);
            u16 tmp[8];
            __builtin_memcpy(tmp, &vv, 16);
#pragma unroll
            for (int j2 = 0; j2 < 8; ++j2)
                Vt[(v0 + j2) * 72 + r] = tmp[j2];
        }
        __syncthreads();

        // S strip = Q K^T  (16 q rows x 64 keys), contraction d=128
        f32x4 s[4];
#pragma unroll
        for (int n = 0; n < 4; ++n) s[n] = (f32x4){0.f, 0.f, 0.f, 0.f};
#pragma unroll
        for (int ks = 0; ks < 4; ++ks) {
            bf16x8 aq = *(const bf16x8*)&Qs[(w * 16 + l16) * 136 + ks * 32 + quad * 8];
#pragma unroll
            for (int n = 0; n < 4; ++n) {
                bf16x8 bk = *(const bf16x8*)&Ks[(n * 16 + l16) * 136 + ks * 32 + quad * 8];
                s[n] = __builtin_amdgcn_mfma_f32_16x16x32_bf16(aq, bk, s[n], 0, 0, 0);
            }
        }

        // online softmax; lane owns rows quad*4+r, cols l16 (+16n)
        float mx[4], alpha[4], rs[4];
#pragma unroll
        for (int r = 0; r < 4; ++r) {
#pragma unroll
            for (int n = 0; n < 4; ++n) s[n][r] *= scale;
            mx[r] = fmaxf(fmaxf(s[0][r], s[1][r]), fmaxf(s[2][r], s[3][r]));
        }
#pragma unroll
        for (int d = 1; d < 16; d <<= 1)
#pragma unroll
            for (int r = 0; r < 4; ++r)
                mx[r] = fmaxf(mx[r], __shfl_xor(mx[r], d));
#pragma unroll
        for (int r = 0; r < 4; ++r) {
            float mnew = fmaxf(m_run[r], mx[r]);
            alpha[r] = __expf(m_run[r] - mnew);
            m_run[r] = mnew;
            rs[r] = 0.f;
#pragma unroll
            for (int n = 0; n < 4; ++n) {
                float pv = __expf(s[n][r] - mnew);
                s[n][r] = pv;
                rs[r] += pv;
            }
        }
#pragma unroll
        for (int d = 1; d < 16; d <<= 1)
#pragma unroll
            for (int r = 0; r < 4; ++r)
                rs[r] += __shfl_xor(rs[r], d);
#pragma unroll
        for (int r = 0; r < 4; ++r) {
            l_run[r] = l_run[r] * alpha[r] + rs[r];
#pragma unroll
            for (int n = 0; n < 4; ++n) o[n][r] *= alpha[r];
        }

        // P: C-layout -> LDS (wave-private 16-row strip)
#pragma unroll
        for (int n = 0; n < 4; ++n)
#pragma unroll
            for (int r = 0; r < 4; ++r)
                Ps[(w * 16 + quad * 4 + r) * 72 + n * 16 + l16] = f2bf(s[n][r]);
        __syncthreads();

        // O += P @ V   (contraction over 64 keys)
#pragma unroll
        for (int kk = 0; kk < 2; ++kk) {
            bf16x8 ap = *(const bf16x8*)&Ps[(w * 16 + l16) * 72 + kk * 32 + quad * 8];
#pragma unroll
            for (int n = 0; n < 4; ++n) {
                bf16x8 bv = *(const bf16x8*)&Vt[(n * 16 + l16) * 72 + kk * 32 + quad * 8];
                o[n] = __builtin_amdgcn_mfma_f32_16x16x32_bf16(ap, bv, o[n], 0, 0, 0);
            }
        }
    }

#pragma unroll
    for (int n = 0; n < 4; ++n) {
#pragma unroll
        for (int r = 0; r < 4; ++r) {
            int row = qrow0 + w * 16 + quad * 4 + r;
            int col = h * 64 + n * 16 + l16;
            o_dst[(size_t)row * ldo + col] = f2bf(o[n][r] / l_run[r]);
        }
    }
}

// ---------------------------------------------------------------------------
extern "C" void kernel_launch(void* const* d_in, const int* in_sizes, int n_in,
                              void* d_out, int out_size, void* d_ws, size_t ws_size,
                              hipStream_t stream)
{
    const float* h    = (const float*)d_in[0];
    const float* Wdkv = (const float*)d_in[1];
    const float* bdkv = (const float*)d_in[2];
    const float* Wuk  = (const float*)d_in[3];
    const float* buk  = (const float*)d_in[4];
    const float* Wuv  = (const float*)d_in[5];
    const float* buv  = (const float*)d_in[6];
    const float* Wdq  = (const float*)d_in[7];
    const float* bdq  = (const float*)d_in[8];
    const float* Wuq  = (const float*)d_in[9];
    const float* buq  = (const float*)d_in[10];
    const float* Wqr  = (const float*)d_in[11];
    const float* bqr  = (const float*)d_in[12];
    const float* Wkr  = (const float*)d_in[13];
    const float* bkr  = (const float*)d_in[14];
    const float* Wfc  = (const float*)d_in[15];
    const float* bfc  = (const float*)d_in[16];

    // Workspace layout (98,062,592 B total):
    //   out1      : 8192 x 1088 bf16  [c_kv | c_q | k_r]; attn out -> cols 0..1023
    //   out2a/hbf : 8192 x 2048 bf16  (h-bf16 during stage 1; [k_c|v_c] after)
    //   out2b     : 8192 x 2048 bf16  [q_c | q_r]
    //   w1        : 1152 x 2048 bf16  [Wdkv;Wdq;Wkr;zero-pad]
    //   w2a,w2b   : 2048 x 512 bf16   [Wuk;Wuv], [Wuq;Wqr]
    //   wfc       : 2048 x 1024 bf16
    //   bias_s1   : 1088 fp32 [bdkv|bdq|bkr];  bias_2: 4096 fp32 [buk|buv|buq|bqr]
    char* ws = (char*)d_ws;
    u16* out1   = (u16*)ws;                              // 17,825,792 B
    u16* hbf    = (u16*)(ws + 17825792);                 // 33,554,432 B (= out2a)
    u16* out2a  = hbf;
    u16* out2b  = (u16*)(ws + 51380224);                 // 33,554,432 B
    u16* w1     = (u16*)(ws + 84934656);                 //  4,718,592 B
    u16* w2a    = (u16*)(ws + 89653248);                 //  2,097,152 B
    u16* w2b    = (u16*)(ws + 91750400);                 //  2,097,152 B
    u16* wfc    = (u16*)(ws + 93847552);                 //  4,194,304 B
    float* bias_s1 = (float*)(ws + 98041856);            //      4,352 B
    float* bias_2  = (float*)(ws + 98046208);            //     16,384 B

    // --- conversion pass: h + all weights -> bf16 (8-elem chunks) ---
    Cvt9 cd;
    const float* srcs[9] = { h, Wdkv, Wdq, Wkr, Wuk, Wuv, Wuq, Wqr, Wfc };
    u16* dsts[9] = { hbf, w1, w1 + 512 * 2048, w1 + 1024 * 2048,
                     w2a, w2a + 1024 * 512, w2b, w2b + 1024 * 512, wfc };
    int cnts[9] = { 2097152, 131072, 131072, 16384, 65536, 65536, 65536, 65536, 262144 };
    int acc2 = 0;
    for (int i = 0; i < 9; ++i) { cd.src[i] = srcs[i]; cd.dst[i] = dsts[i]; acc2 += cnts[i]; cd.end[i] = acc2; }
    cvt_all<<<(acc2 + 255) / 256, 256, 0, stream>>>(cd, acc2);
    // zero-pad w1 rows 1088..1151
    hipMemsetAsync(w1 + 1088 * 2048, 0, 64 * 2048 * sizeof(u16), stream);

    // --- bias concat (fp32) ---
    Cpy7 bc;
    const float* bs[7] = { bdkv, bdq, bkr, buk, buv, buq, bqr };
    float* bd[7] = { bias_s1, bias_s1 + 512, bias_s1 + 1024,
                     bias_2, bias_2 + 1024, bias_2 + 2048, bias_2 + 3072 };
    int bn[7] = { 512, 512, 64, 1024, 1024, 1024, 1024 };
    int bacc = 0;
    for (int i = 0; i < 7; ++i) { bc.src[i] = bs[i]; bc.dst[i] = bd[i]; bacc += bn[i]; bc.end[i] = bacc; }
    copy_f32<<<(bacc + 255) / 256, 256, 0, stream>>>(bc, bacc);

    // --- stage 1: [c_kv|c_q|k_r] = hbf @ w1^T, N=1088, K=2048 ---
    gemm_v3<false><<<dim3(64, 9), 256, 0, stream>>>(
        hbf, w1, out1, bias_s1,
        hbf, w1, out1, bias_s1, 9, 2048, 2048, 1088, 1088, 2048);
    rope_inplace<<<1024, 256, 0, stream>>>(out1, 1088, 1024, 32, 8192 * 32);   // k_r

    // --- stage 2 (fused 2a+2b): K=512, N=2048 each half ---
    gemm_v3<false><<<dim3(64, 32), 256, 0, stream>>>(
        out1,       w2a, out2a, bias_2,
        out1 + 512, w2b, out2b, bias_2 + 2048, 16, 1088, 512, 2048, 2048, 512);
    rope_inplace<<<16384, 256, 0, stream>>>(out2b, 2048, 1024, 512, 8192 * 512);  // q_r

    // --- attention: output overwrites out1 cols 0..1023 (c_kv/c_q dead) ---
    attn_kernel<<<dim3(8, 16, 16), 256, 0, stream>>>(out2b, out2a, out1, out1, 1088);

    // --- final projection: d_out = attn @ wfc^T, fp32 out ---
    gemm_v3<true><<<dim3(64, 16), 256, 0, stream>>>(
        out1, wfc, d_out, bfc,
        out1, wfc, d_out, bfc, 16, 1088, 1024, 2048, 2048, 1024);
}